// Round 5
// baseline (4468.884 us; speedup 1.0000x reference)
//
#include <hip/hip_runtime.h>

// TopKActivationMLP: B=16384, IN=1024, H=2048, K=256, NC=1000
//   h0 = relu(topk256(x @ W0^T + b0))
//   h1 = relu(topk256(h0 @ W1^T + b1))
//   out = h1 @ Wc^T + bc
//
// R9: (a) spmm v4 — slab split into two 32KB half-arrays (Ws0=cols0-3 @
// k*16, Ws1=cols4-7 @ 32KB+k*16). Old [k][8] layout (32B stride) made every
// ds_read_b128 start at bank {0,8,16,24}: banks 4-7/12-15/20-23/28-31 were
// UNREACHABLE -> hard 2x LDS throughput loss. New stride 16B -> start bank
// (4k)%32 uniform over all 8 groups. Same reads, same FMA order ->
// bit-identical. (b) gemm split 4-way (~300us each) so the largest non-gemm
// kernel finally surfaces in rocprof top-5 with its counters.
// Value path bit-identical throughout (fp64 keys, p-ascending FMA).

#define B_SZ 16384
#define IN_SZ 1024
#define H_SZ 2048
#define K_TOP 256
#define NC_SZ 1000
#define NC_PAD 1008  // 126 blocks of 8

// ---------- dense fp64 GEMM (layer 0): C = A @ Bt^T + bias --------------
__global__ __launch_bounds__(256, 4) void gemm_bt_v2(
    const float* __restrict__ A, const float* __restrict__ Bt,
    const float* __restrict__ bias, double* __restrict__ C,
    int M, int N, int Kd) {
  __shared__ double As[16][130];
  __shared__ double Bs[16][66];
  const int tid = threadIdx.x;
  const int tx = tid & 15;
  const int tym = tid >> 4;
  const int m0 = blockIdx.y * 128;
  const int n0 = blockIdx.x * 64;

  double acc[8][4];
#pragma unroll
  for (int i = 0; i < 8; ++i)
#pragma unroll
    for (int j = 0; j < 4; ++j) acc[i][j] = 0.0;

  for (int k0 = 0; k0 < Kd; k0 += 16) {
#pragma unroll
    for (int l = 0; l < 8; ++l) {
      const int idx = l * 256 + tid;
      const int rr = idx >> 4;
      const int kk = idx & 15;
      As[kk][rr] = (double)A[(size_t)(m0 + rr) * Kd + (k0 + kk)];
    }
#pragma unroll
    for (int l = 0; l < 4; ++l) {
      const int idx = l * 256 + tid;
      const int rr = idx >> 4;
      const int kk = idx & 15;
      Bs[kk][rr] = (double)Bt[(size_t)(n0 + rr) * Kd + (k0 + kk)];
    }
    __syncthreads();
#pragma unroll 4
    for (int kk = 0; kk < 16; ++kk) {
      double a[8], b[4];
#pragma unroll
      for (int i = 0; i < 8; ++i) a[i] = As[kk][tym + 16 * i];
#pragma unroll
      for (int j = 0; j < 4; ++j) b[j] = Bs[kk][tx + 16 * j];
#pragma unroll
      for (int i = 0; i < 8; ++i)
#pragma unroll
        for (int j = 0; j < 4; ++j) acc[i][j] = fma(a[i], b[j], acc[i][j]);
    }
    __syncthreads();
  }
#pragma unroll
  for (int i = 0; i < 8; ++i) {
    const int r = m0 + tym + 16 * i;
#pragma unroll
    for (int j = 0; j < 4; ++j) {
      const int c = n0 + tx + 16 * j;
      C[(size_t)r * N + c] = acc[i][j] + (double)bias[c];
    }
  }
}

__device__ __forceinline__ int blockReduceSum(int v, int* sred) {
#pragma unroll
  for (int o = 32; o > 0; o >>= 1) v += __shfl_down(v, o);
  const int tid = threadIdx.x;
  if ((tid & 63) == 0) sred[tid >> 6] = v;
  __syncthreads();
  int t = 0;
  if (tid < 4) t = sred[tid];
  t += __shfl_down(t, 2);
  t += __shfl_down(t, 1);
  if (tid == 0) sred[0] = t;
  __syncthreads();
  const int r = sred[0];
  __syncthreads();
  return r;
}

// ---------- top-k select + compact to exactly 256 ------------------------
// Output: pvk transposed-packed: pvk[(row>>6)*256*64 + pos*64 + (row&63)]
//         = {key: f64 bits of relu'd value, idx}
__global__ __launch_bounds__(256) void topk_compact_v3(
    const double* __restrict__ h, longlong2* __restrict__ pvk) {
  __shared__ int sred[4];
  __shared__ int hist[256];
  __shared__ int swsum[4];
  __shared__ unsigned int sprefix;
  __shared__ int srem;
  __shared__ int scnt;
  __shared__ unsigned long long ckey[128];
  __shared__ int cidx[128];
  __shared__ double sval[H_SZ];
  __shared__ unsigned char sflag[H_SZ];
  const int tid = threadIdx.x;
  const int row = blockIdx.x;
  const double* hr = h + (size_t)row * H_SZ;

  double myv[8];
  unsigned long long myk64[8];
  unsigned int myk[8];
#pragma unroll
  for (int l = 0; l < 8; ++l) {
    const int i = l * 256 + tid;
    const double v = hr[i];
    myv[l] = v;
    unsigned long long b = (unsigned long long)__double_as_longlong(v);
    unsigned long long u =
        (b & 0x8000000000000000ULL) ? ~b : (b | 0x8000000000000000ULL);
    myk64[l] = u;
    myk[l] = (unsigned int)(u >> 32);
  }

  // ---- 4-round histogram radix select on the high-32 key ----
  unsigned int prefix = 0;   // decided high bits
  unsigned int pmask = 0;    // mask of decided high bits
  int remaining = K_TOP;
#pragma unroll
  for (int round = 0; round < 4; ++round) {
    const int shift = 24 - 8 * round;
    hist[tid] = 0;
    __syncthreads();
    if (round == 0) {
      // wave-aggregated histogram: bins are exponent-concentrated, so the
      // distinct-bin count per wave is tiny; one atomic per distinct bin.
      // Bounded (each iter retires >=1 lane -> <=64 needed) + fallback.
#pragma unroll
      for (int l = 0; l < 8; ++l) {
        const int bin = (int)(myk[l] >> 24);
        bool pending = true;
        for (int it = 0; it < 64; ++it) {
          if (!__any(pending)) break;
          const unsigned long long m = __ballot(pending);
          const int src = (int)__ffsll(m) - 1;
          const int b = __shfl(bin, src);
          const bool mine = pending && (bin == b);
          const unsigned long long grp = __ballot(mine);
          if ((tid & 63) == src) atomicAdd(&hist[b], (int)__popcll(grp));
          if (mine) pending = false;
        }
        if (pending) atomicAdd(&hist[bin], 1);  // never in practice
      }
    } else {
#pragma unroll
      for (int l = 0; l < 8; ++l) {
        const unsigned int u = myk[l];
        if ((u & pmask) == prefix) atomicAdd(&hist[(u >> shift) & 255], 1);
      }
    }
    __syncthreads();
    const int v = hist[tid];  // thread tid owns bin tid
    // inclusive suffix-sum within 64-lane chunk
    int s = v;
#pragma unroll
    for (int off = 1; off < 64; off <<= 1) {
      const int t = __shfl_down(s, off);
      if ((tid & 63) + off < 64) s += t;
    }
    if ((tid & 63) == 0) swsum[tid >> 6] = s;
    __syncthreads();
    int S = s;
    for (int c = (tid >> 6) + 1; c < 4; ++c) S += swsum[c];
    // unique bucket: suffix crosses `remaining` here (only v>0 can match)
    if (S >= remaining && (S - v) < remaining) {
      sprefix = prefix | ((unsigned int)tid << shift);
      srem = remaining - (S - v);
    }
    __syncthreads();
    prefix = sprefix;
    remaining = srem;
    pmask |= (0xFFu << shift);
  }

  const unsigned int T = prefix;
  const int need_eq = remaining;  // == K_TOP - count(key > T)

  int ce = 0;
#pragma unroll
  for (int l = 0; l < 8; ++l) ce += (myk[l] == T) ? 1 : 0;
  const int count_eq = blockReduceSum(ce, sred);

  bool keep[8];
#pragma unroll
  for (int l = 0; l < 8; ++l) keep[l] = (myk[l] > T);

  if (count_eq == need_eq) {
#pragma unroll
    for (int l = 0; l < 8; ++l) keep[l] = keep[l] || (myk[l] == T);
  } else {
    // rare: high-32 boundary collision -> exact 64-bit + index resolve
    if (tid == 0) scnt = 0;
    __syncthreads();
    int mypos[8];
#pragma unroll
    for (int l = 0; l < 8; ++l) mypos[l] = -1;
#pragma unroll
    for (int l = 0; l < 8; ++l) {
      if (myk[l] == T) {
        const int p = atomicAdd(&scnt, 1);
        if (p < 128) {
          ckey[p] = myk64[l];
          cidx[p] = l * 256 + tid;
          mypos[l] = p;
        }
      }
    }
    __syncthreads();
    const int c = (scnt < 128) ? scnt : 128;
#pragma unroll
    for (int l = 0; l < 8; ++l) {
      if (mypos[l] >= 0) {
        const unsigned long long k = ckey[mypos[l]];
        const int ii = cidx[mypos[l]];
        int rank = 0;
        for (int j = 0; j < c; ++j)
          rank += ((ckey[j] > k) || (ckey[j] == k && cidx[j] < ii)) ? 1 : 0;
        keep[l] = (rank < need_eq);
      }
    }
  }

#pragma unroll
  for (int l = 0; l < 8; ++l) {
    const int i = l * 256 + tid;
    sflag[i] = keep[l] ? 1 : 0;
    sval[i] = (keep[l] && myv[l] > 0.0) ? myv[l] : 0.0;
  }
  __syncthreads();

  // compact: thread t owns [8t, 8t+8); exclusive scan -> ascending index
  const int base_i = tid * 8;
  int cnt = 0;
  int pre[8];
#pragma unroll
  for (int j = 0; j < 8; ++j) {
    pre[j] = cnt;
    cnt += sflag[base_i + j];
  }
  int inc = cnt;
#pragma unroll
  for (int o = 1; o < 64; o <<= 1) {
    const int t = __shfl_up(inc, o);
    if ((tid & 63) >= o) inc += t;
  }
  if ((tid & 63) == 63) swsum[tid >> 6] = inc;
  __syncthreads();

  int wbase = 0;
  for (int w = 0; w < (tid >> 6); ++w) wbase += swsum[w];
  const int ebase = wbase + inc - cnt;

  // transposed-packed output: [row>>6][pos][row&63]
  longlong2* __restrict__ po =
      pvk + ((size_t)(row >> 6) * K_TOP) * 64 + (row & 63);
#pragma unroll
  for (int j = 0; j < 8; ++j) {
    if (sflag[base_i + j]) {
      const int pos = ebase + pre[j];
      if (pos < K_TOP) {
        longlong2 e;
        e.x = __double_as_longlong(sval[base_i + j]);
        e.y = (long long)(base_i + j);
        po[(size_t)pos * 64] = e;
      }
    }
  }
}

// ---------- pack W [N][K] -> split-half blocked --------------------------
// out[cb][half][k][4], cb = n>>3, half = (n>>2)&1: matches the split-half
// LDS slab (Ws0 = cols 0-3 @ k*16B, Ws1 = cols 4-7 @ 32KB + k*16B).
__global__ __launch_bounds__(256) void pack_w_split(
    const float* __restrict__ in, float* __restrict__ out, int N, int Kd,
    int Npad) {
  __shared__ float t[32][33];
  const int bx = blockIdx.x * 32;  // k
  const int by = blockIdx.y * 32;  // n
#pragma unroll
  for (int s = 0; s < 32; s += 8) {
    const int n = by + threadIdx.y + s;
    const int k = bx + threadIdx.x;
    t[threadIdx.y + s][threadIdx.x] =
        (n < N && k < Kd) ? in[(size_t)n * Kd + k] : 0.f;
  }
  __syncthreads();
#pragma unroll
  for (int s = 0; s < 32; s += 8) {
    const int k = bx + threadIdx.y + s;
    const int n = by + threadIdx.x;
    if (k < Kd && n < Npad)
      out[(size_t)(n >> 3) * (Kd * 8) + (size_t)((n >> 2) & 1) * (Kd * 4) +
          (size_t)k * 4 + (n & 3)] = t[threadIdx.x][threadIdx.y + s];
  }
}

// ---------- fixed-trip SpMM over 8-col W slab (v4) -----------------------
// Split-half slab: Ws0[k][0..3] @ byte k*16, Ws1[k][4..7] @ 32KB + k*16.
// Start bank (4k)%32 uniform over all 8 bank-groups (old 32B-stride layout
// could only ever touch banks {0-3,8-11,16-19,24-27}). 1024-thread blocks,
// 2/CU. Per p: 1 coalesced 16B pvk load + 2 ds_read_b128, 8 indep FMA.
// p ascending, same FMA order -> bit-identical outputs.
template <typename ACC_T, typename OUT_T>
__global__ __launch_bounds__(1024) void spmm8_v4(
    const longlong2* __restrict__ pvk, const float* __restrict__ Wblk,
    const float* __restrict__ bias, OUT_T* __restrict__ out, int Ncols,
    int strideN) {
  __shared__ float Ws[H_SZ * 8];  // 64 KB: [0..32KB)=cols0-3, [32KB..)=cols4-7
  const int tid = threadIdx.x;
  const int cb = blockIdx.x;
  const float* src = Wblk + (size_t)cb * (H_SZ * 8);
#pragma unroll
  for (int i = 0; i < 4; ++i)
    ((float4*)Ws)[i * 1024 + tid] = ((const float4*)src)[i * 1024 + tid];
  __syncthreads();

  const int nb = cb * 8;
  const int r = blockIdx.y * 1024 + tid;
  const longlong2* __restrict__ pr =
      pvk + ((size_t)(r >> 6) * K_TOP) * 64 + (r & 63);
  const float4* __restrict__ W0 = (const float4*)Ws;           // [k] cols0-3
  const float4* __restrict__ W1 = (const float4*)(Ws + H_SZ * 4);  // cols4-7

  ACC_T a[8];
#pragma unroll
  for (int c = 0; c < 8; ++c) a[c] = (ACC_T)0;
#pragma unroll 4
  for (int p = 0; p < K_TOP; ++p) {
    const longlong2 e = pr[(size_t)p * 64];
    const ACC_T v = (ACC_T)__longlong_as_double(e.x);
    const int k = (int)e.y;
    const float4 w0 = W0[k];
    const float4 w1 = W1[k];
    a[0] += (ACC_T)w0.x * v;
    a[1] += (ACC_T)w0.y * v;
    a[2] += (ACC_T)w0.z * v;
    a[3] += (ACC_T)w0.w * v;
    a[4] += (ACC_T)w1.x * v;
    a[5] += (ACC_T)w1.y * v;
    a[6] += (ACC_T)w1.z * v;
    a[7] += (ACC_T)w1.w * v;
  }
  OUT_T* __restrict__ orow = out + (size_t)r * strideN + nb;
  if (nb + 7 < Ncols) {
#pragma unroll
    for (int c = 0; c < 8; ++c) orow[c] = (OUT_T)(a[c] + (ACC_T)bias[nb + c]);
  } else {
#pragma unroll
    for (int c = 0; c < 8; ++c)
      if (nb + c < Ncols) orow[c] = (OUT_T)(a[c] + (ACC_T)bias[nb + c]);
  }
}

extern "C" void kernel_launch(void* const* d_in, const int* in_sizes, int n_in,
                              void* d_out, int out_size, void* d_ws, size_t ws_size,
                              hipStream_t stream) {
  const float* x  = (const float*)d_in[0];
  const float* W0 = (const float*)d_in[1];
  const float* b0 = (const float*)d_in[2];
  const float* W1 = (const float*)d_in[3];
  const float* b1 = (const float*)d_in[4];
  const float* Wc = (const float*)d_in[5];
  const float* bc = (const float*)d_in[6];
  float* out = (float*)d_out;

  auto align256 = [](size_t v) { return (v + 255) & ~(size_t)255; };
  char* base = (char*)d_ws;
  size_t off = 0;
  float* W1blk = (float*)(base + off);
  off = align256(off + (size_t)H_SZ * H_SZ * sizeof(float));       // 16.8 MB
  float* Wcblk = (float*)(base + off);
  off = align256(off + (size_t)H_SZ * NC_PAD * sizeof(float));     // 8.26 MB
  const size_t fixed = off;

  const size_t per_row =
      (size_t)H_SZ * 8 + (size_t)K_TOP * 16;  // hd + pvk
  int chunkB = B_SZ;
  while (fixed + (size_t)chunkB * per_row + 4096 > ws_size && chunkB > 1024)
    chunkB >>= 1;

  double* hd = (double*)(base + off);
  off = align256(off + (size_t)chunkB * H_SZ * sizeof(double));
  longlong2* pvk = (longlong2*)(base + off);

  const dim3 blk(256);
  // one-time weight pack to split-half blocked layout
  pack_w_split<<<dim3(H_SZ / 32, H_SZ / 32), dim3(32, 8), 0, stream>>>(
      W1, W1blk, H_SZ, H_SZ, H_SZ);
  pack_w_split<<<dim3(H_SZ / 32, (NC_PAD + 31) / 32), dim3(32, 8), 0,
                 stream>>>(Wc, Wcblk, NC_SZ, H_SZ, NC_PAD);

  for (int m0 = 0; m0 < B_SZ; m0 += chunkB) {
    const int M = chunkB;
    // layer 0: dense fp64, split 4-way so non-gemm kernels surface in top-5
    const int Mq = M / 4;
    for (int q = 0; q < 4; ++q)
      gemm_bt_v2<<<dim3(H_SZ / 64, Mq / 128), blk, 0, stream>>>(
          x + (size_t)(m0 + q * Mq) * IN_SZ, W0, b0,
          hd + (size_t)q * Mq * H_SZ, Mq, H_SZ, IN_SZ);
    topk_compact_v3<<<dim3(M), blk, 0, stream>>>(hd, pvk);
    // layer 1: f64-exact SpMM -> dense hd
    spmm8_v4<double, double><<<dim3(H_SZ / 8, M / 1024), dim3(1024), 0,
                               stream>>>(pvk, W1blk, b1, hd, H_SZ, H_SZ);
    topk_compact_v3<<<dim3(M), blk, 0, stream>>>(hd, pvk);
    // layer 2: f32 SpMM -> output
    spmm8_v4<float, float><<<dim3(NC_PAD / 8, M / 1024), dim3(1024), 0,
                             stream>>>(pvk, Wcblk, bc,
                                       out + (size_t)m0 * NC_SZ, NC_SZ,
                                       NC_SZ);
  }
}

// Round 7
// 3618.974 us; speedup vs baseline: 1.2348x; 1.2348x over previous
//
#include <hip/hip_runtime.h>

// TopKActivationMLP: B=16384, IN=1024, H=2048, K=256, NC=1000
//   h0 = relu(topk256(x @ W0^T + b0))
//   h1 = relu(topk256(h0 @ W1^T + b1))
//   out = h1 @ Wc^T + bc
//
// R11: f32-selection FALSIFIED (R10: absmax 0.0488 = 1-2 boundary flips;
// min gap over 32768 selections < f32 noise). CONSTRAINT: all sums feeding
// a top-k must be f64-exact; stored layer-1 pv must stay f64.
// This round = best proven pieces: f64 gemm (2-way split), f64 topk
// (ballot round-0), layer-1 spmm8_v4 f64 split-half slab (R9-measured 441us
// = LDS read roofline). NEW (safe): topk#2 emits int2{f32 val, idx} — layer2
// always consumed (float)pv, so rounding at emit == rounding at consume,
// bit-identical output; halves layer-2's pvk cache stream.

#define B_SZ 16384
#define IN_SZ 1024
#define H_SZ 2048
#define K_TOP 256
#define NC_SZ 1000
#define NC_PAD 1008  // 126 blocks of 8

// ---------- dense fp64 GEMM (layer 0): C = A @ Bt^T + bias --------------
__global__ __launch_bounds__(256, 4) void gemm_bt_v2(
    const float* __restrict__ A, const float* __restrict__ Bt,
    const float* __restrict__ bias, double* __restrict__ C,
    int M, int N, int Kd) {
  __shared__ double As[16][130];
  __shared__ double Bs[16][66];
  const int tid = threadIdx.x;
  const int tx = tid & 15;
  const int tym = tid >> 4;
  const int m0 = blockIdx.y * 128;
  const int n0 = blockIdx.x * 64;

  double acc[8][4];
#pragma unroll
  for (int i = 0; i < 8; ++i)
#pragma unroll
    for (int j = 0; j < 4; ++j) acc[i][j] = 0.0;

  for (int k0 = 0; k0 < Kd; k0 += 16) {
#pragma unroll
    for (int l = 0; l < 8; ++l) {
      const int idx = l * 256 + tid;
      const int rr = idx >> 4;
      const int kk = idx & 15;
      As[kk][rr] = (double)A[(size_t)(m0 + rr) * Kd + (k0 + kk)];
    }
#pragma unroll
    for (int l = 0; l < 4; ++l) {
      const int idx = l * 256 + tid;
      const int rr = idx >> 4;
      const int kk = idx & 15;
      Bs[kk][rr] = (double)Bt[(size_t)(n0 + rr) * Kd + (k0 + kk)];
    }
    __syncthreads();
#pragma unroll 4
    for (int kk = 0; kk < 16; ++kk) {
      double a[8], b[4];
#pragma unroll
      for (int i = 0; i < 8; ++i) a[i] = As[kk][tym + 16 * i];
#pragma unroll
      for (int j = 0; j < 4; ++j) b[j] = Bs[kk][tx + 16 * j];
#pragma unroll
      for (int i = 0; i < 8; ++i)
#pragma unroll
        for (int j = 0; j < 4; ++j) acc[i][j] = fma(a[i], b[j], acc[i][j]);
    }
    __syncthreads();
  }
#pragma unroll
  for (int i = 0; i < 8; ++i) {
    const int r = m0 + tym + 16 * i;
#pragma unroll
    for (int j = 0; j < 4; ++j) {
      const int c = n0 + tx + 16 * j;
      C[(size_t)r * N + c] = acc[i][j] + (double)bias[c];
    }
  }
}

__device__ __forceinline__ int blockReduceSum(int v, int* sred) {
#pragma unroll
  for (int o = 32; o > 0; o >>= 1) v += __shfl_down(v, o);
  const int tid = threadIdx.x;
  if ((tid & 63) == 0) sred[tid >> 6] = v;
  __syncthreads();
  int t = 0;
  if (tid < 4) t = sred[tid];
  t += __shfl_down(t, 2);
  t += __shfl_down(t, 1);
  if (tid == 0) sred[0] = t;
  __syncthreads();
  const int r = sred[0];
  __syncthreads();
  return r;
}

// ---------- top-k select + compact to exactly 256 (f64 selection) --------
// Selection on f64 keys (exact, matches proven path). Emit transposed-packed
// at [(row>>6)*256 + pos]*64 + (row&63):
//   F32OUT=false -> longlong2{f64 bits of relu'd val, idx}   (layer-1 input)
//   F32OUT=true  -> int2{f32 bits of relu'd val, idx}        (layer-2 input;
//                   rounding at emit == old (float)pv at consume)
template <bool F32OUT>
__global__ __launch_bounds__(256) void topk_compact_v4(
    const double* __restrict__ h, void* __restrict__ pvk_raw) {
  __shared__ int sred[4];
  __shared__ int hist[256];
  __shared__ int swsum[4];
  __shared__ unsigned int sprefix;
  __shared__ int srem;
  __shared__ int scnt;
  __shared__ unsigned long long ckey[128];
  __shared__ int cidx[128];
  __shared__ double sval[H_SZ];
  __shared__ unsigned char sflag[H_SZ];
  const int tid = threadIdx.x;
  const int row = blockIdx.x;
  const double* hr = h + (size_t)row * H_SZ;

  double myv[8];
  unsigned long long myk64[8];
  unsigned int myk[8];
#pragma unroll
  for (int l = 0; l < 8; ++l) {
    const int i = l * 256 + tid;
    const double v = hr[i];
    myv[l] = v;
    unsigned long long b = (unsigned long long)__double_as_longlong(v);
    unsigned long long u =
        (b & 0x8000000000000000ULL) ? ~b : (b | 0x8000000000000000ULL);
    myk64[l] = u;
    myk[l] = (unsigned int)(u >> 32);
  }

  // ---- 4-round histogram radix select on the high-32 key ----
  unsigned int prefix = 0;   // decided high bits
  unsigned int pmask = 0;    // mask of decided high bits
  int remaining = K_TOP;
#pragma unroll
  for (int round = 0; round < 4; ++round) {
    const int shift = 24 - 8 * round;
    hist[tid] = 0;
    __syncthreads();
    if (round == 0) {
      // wave-aggregated histogram: top byte is exponent-concentrated ->
      // plain same-bin LDS atomics would serialize ~64-deep.
      // Bounded (each iter retires >=1 lane) + fallback.
#pragma unroll
      for (int l = 0; l < 8; ++l) {
        const int bin = (int)(myk[l] >> 24);
        bool pending = true;
        for (int it = 0; it < 64; ++it) {
          if (!__any(pending)) break;
          const unsigned long long m = __ballot(pending);
          const int src = (int)__ffsll(m) - 1;
          const int b = __shfl(bin, src);
          const bool mine = pending && (bin == b);
          const unsigned long long grp = __ballot(mine);
          if ((tid & 63) == src) atomicAdd(&hist[b], (int)__popcll(grp));
          if (mine) pending = false;
        }
        if (pending) atomicAdd(&hist[bin], 1);  // never in practice
      }
    } else {
#pragma unroll
      for (int l = 0; l < 8; ++l) {
        const unsigned int u = myk[l];
        if ((u & pmask) == prefix) atomicAdd(&hist[(u >> shift) & 255], 1);
      }
    }
    __syncthreads();
    const int v = hist[tid];  // thread tid owns bin tid
    int s = v;                // inclusive suffix-sum within 64-lane chunk
#pragma unroll
    for (int off = 1; off < 64; off <<= 1) {
      const int t = __shfl_down(s, off);
      if ((tid & 63) + off < 64) s += t;
    }
    if ((tid & 63) == 0) swsum[tid >> 6] = s;
    __syncthreads();
    int S = s;
    for (int c = (tid >> 6) + 1; c < 4; ++c) S += swsum[c];
    if (S >= remaining && (S - v) < remaining) {  // unique crossing bucket
      sprefix = prefix | ((unsigned int)tid << shift);
      srem = remaining - (S - v);
    }
    __syncthreads();
    prefix = sprefix;
    remaining = srem;
    pmask |= (0xFFu << shift);
  }

  const unsigned int T = prefix;
  const int need_eq = remaining;  // == K_TOP - count(key > T)

  int ce = 0;
#pragma unroll
  for (int l = 0; l < 8; ++l) ce += (myk[l] == T) ? 1 : 0;
  const int count_eq = blockReduceSum(ce, sred);

  bool keep[8];
#pragma unroll
  for (int l = 0; l < 8; ++l) keep[l] = (myk[l] > T);

  if (count_eq == need_eq) {
#pragma unroll
    for (int l = 0; l < 8; ++l) keep[l] = keep[l] || (myk[l] == T);
  } else {
    // rare: high-32 boundary collision -> exact 64-bit + index resolve
    if (tid == 0) scnt = 0;
    __syncthreads();
    int mypos[8];
#pragma unroll
    for (int l = 0; l < 8; ++l) mypos[l] = -1;
#pragma unroll
    for (int l = 0; l < 8; ++l) {
      if (myk[l] == T) {
        const int p = atomicAdd(&scnt, 1);
        if (p < 128) {
          ckey[p] = myk64[l];
          cidx[p] = l * 256 + tid;
          mypos[l] = p;
        }
      }
    }
    __syncthreads();
    const int c = (scnt < 128) ? scnt : 128;
#pragma unroll
    for (int l = 0; l < 8; ++l) {
      if (mypos[l] >= 0) {
        const unsigned long long k = ckey[mypos[l]];
        const int ii = cidx[mypos[l]];
        int rank = 0;
        for (int j = 0; j < c; ++j)
          rank += ((ckey[j] > k) || (ckey[j] == k && cidx[j] < ii)) ? 1 : 0;
        keep[l] = (rank < need_eq);
      }
    }
  }

#pragma unroll
  for (int l = 0; l < 8; ++l) {
    const int i = l * 256 + tid;
    sflag[i] = keep[l] ? 1 : 0;
    sval[i] = (keep[l] && myv[l] > 0.0) ? myv[l] : 0.0;  // relu
  }
  __syncthreads();

  // compact: thread t owns [8t, 8t+8); exclusive scan -> ascending index
  const int base_i = tid * 8;
  int cnt = 0;
  int pre[8];
#pragma unroll
  for (int j = 0; j < 8; ++j) {
    pre[j] = cnt;
    cnt += sflag[base_i + j];
  }
  int inc = cnt;
#pragma unroll
  for (int o = 1; o < 64; o <<= 1) {
    const int t = __shfl_up(inc, o);
    if ((tid & 63) >= o) inc += t;
  }
  if ((tid & 63) == 63) swsum[tid >> 6] = inc;
  __syncthreads();

  int wbase = 0;
  for (int w = 0; w < (tid >> 6); ++w) wbase += swsum[w];
  const int ebase = wbase + inc - cnt;

  const size_t obase = ((size_t)(row >> 6) * K_TOP) * 64 + (row & 63);
#pragma unroll
  for (int j = 0; j < 8; ++j) {
    if (sflag[base_i + j]) {
      const int pos = ebase + pre[j];
      if (pos < K_TOP) {
        if (F32OUT) {
          int2 e;
          e.x = __float_as_int((float)sval[base_i + j]);
          e.y = base_i + j;
          ((int2*)pvk_raw)[obase + (size_t)pos * 64] = e;
        } else {
          longlong2 e;
          e.x = __double_as_longlong(sval[base_i + j]);
          e.y = (long long)(base_i + j);
          ((longlong2*)pvk_raw)[obase + (size_t)pos * 64] = e;
        }
      }
    }
  }
}

// ---------- pack W [N][K] -> split-half blocked --------------------------
// out[cb][half][k][4], cb = n>>3, half = (n>>2)&1: matches the split-half
// LDS slab (Ws0 = cols 0-3 @ k*16B, Ws1 = cols 4-7 @ 32KB + k*16B).
__global__ __launch_bounds__(256) void pack_w_split(
    const float* __restrict__ in, float* __restrict__ out, int N, int Kd,
    int Npad) {
  __shared__ float t[32][33];
  const int bx = blockIdx.x * 32;  // k
  const int by = blockIdx.y * 32;  // n
#pragma unroll
  for (int s = 0; s < 32; s += 8) {
    const int n = by + threadIdx.y + s;
    const int k = bx + threadIdx.x;
    t[threadIdx.y + s][threadIdx.x] =
        (n < N && k < Kd) ? in[(size_t)n * Kd + k] : 0.f;
  }
  __syncthreads();
#pragma unroll
  for (int s = 0; s < 32; s += 8) {
    const int k = bx + threadIdx.y + s;
    const int n = by + threadIdx.x;
    if (k < Kd && n < Npad)
      out[(size_t)(n >> 3) * (Kd * 8) + (size_t)((n >> 2) & 1) * (Kd * 4) +
          (size_t)k * 4 + (n & 3)] = t[threadIdx.x][threadIdx.y + s];
  }
}

// ---------- fixed-trip f64 SpMM over 8-col W slab (layer 1) --------------
// R9-verified at LDS read roofline (441us): split-half slab, start bank
// (4k)%32 uniform. 1024-thread blocks, 2/CU. Arithmetic identical to R9
// spmm8_v4<double,double> (p ascending) -> bit-identical h1.
__global__ __launch_bounds__(1024) void spmm8_v4d(
    const longlong2* __restrict__ pvk, const float* __restrict__ Wblk,
    const float* __restrict__ bias, double* __restrict__ out, int Ncols,
    int strideN) {
  __shared__ float Ws[H_SZ * 8];  // 64 KB: [0..32KB)=cols0-3, [32KB..)=cols4-7
  const int tid = threadIdx.x;
  const int cb = blockIdx.x;
  const float* src = Wblk + (size_t)cb * (H_SZ * 8);
#pragma unroll
  for (int i = 0; i < 4; ++i)
    ((float4*)Ws)[i * 1024 + tid] = ((const float4*)src)[i * 1024 + tid];
  __syncthreads();

  const int nb = cb * 8;
  const int r = blockIdx.y * 1024 + tid;
  const longlong2* __restrict__ pr =
      pvk + ((size_t)(r >> 6) * K_TOP) * 64 + (r & 63);
  const float4* __restrict__ W0 = (const float4*)Ws;               // cols 0-3
  const float4* __restrict__ W1 = (const float4*)(Ws + H_SZ * 4);  // cols 4-7

  double a[8];
#pragma unroll
  for (int c = 0; c < 8; ++c) a[c] = 0.0;
#pragma unroll 4
  for (int p = 0; p < K_TOP; ++p) {
    const longlong2 e = pr[(size_t)p * 64];
    const double v = __longlong_as_double(e.x);
    const int k = (int)e.y;
    const float4 w0 = W0[k];
    const float4 w1 = W1[k];
    a[0] += (double)w0.x * v;
    a[1] += (double)w0.y * v;
    a[2] += (double)w0.z * v;
    a[3] += (double)w0.w * v;
    a[4] += (double)w1.x * v;
    a[5] += (double)w1.y * v;
    a[6] += (double)w1.z * v;
    a[7] += (double)w1.w * v;
  }
  double* __restrict__ orow = out + (size_t)r * strideN + nb;
#pragma unroll
  for (int c = 0; c < 8; ++c) orow[c] = a[c] + (double)bias[nb + c];
}

// ---------- fixed-trip f32 SpMM over 8-col W slab (layer 2) --------------
// Same structure; int2 pvk (f32 val pre-rounded at emit == old (float)pv).
__global__ __launch_bounds__(1024) void spmm8_v4f(
    const int2* __restrict__ pvk, const float* __restrict__ Wblk,
    const float* __restrict__ bias, float* __restrict__ out, int Ncols,
    int strideN) {
  __shared__ float Ws[H_SZ * 8];  // 64 KB
  const int tid = threadIdx.x;
  const int cb = blockIdx.x;
  const float* src = Wblk + (size_t)cb * (H_SZ * 8);
#pragma unroll
  for (int i = 0; i < 4; ++i)
    ((float4*)Ws)[i * 1024 + tid] = ((const float4*)src)[i * 1024 + tid];
  __syncthreads();

  const int nb = cb * 8;
  const int r = blockIdx.y * 1024 + tid;
  const int2* __restrict__ pr =
      pvk + ((size_t)(r >> 6) * K_TOP) * 64 + (r & 63);
  const float4* __restrict__ W0 = (const float4*)Ws;               // cols 0-3
  const float4* __restrict__ W1 = (const float4*)(Ws + H_SZ * 4);  // cols 4-7

  float a[8];
#pragma unroll
  for (int c = 0; c < 8; ++c) a[c] = 0.f;
#pragma unroll 4
  for (int p = 0; p < K_TOP; ++p) {
    const int2 e = pr[(size_t)p * 64];
    const float v = __int_as_float(e.x);
    const int k = e.y;
    const float4 w0 = W0[k];
    const float4 w1 = W1[k];
    a[0] += w0.x * v;
    a[1] += w0.y * v;
    a[2] += w0.z * v;
    a[3] += w0.w * v;
    a[4] += w1.x * v;
    a[5] += w1.y * v;
    a[6] += w1.z * v;
    a[7] += w1.w * v;
  }
  float* __restrict__ orow = out + (size_t)r * strideN + nb;
  if (nb + 7 < Ncols) {
#pragma unroll
    for (int c = 0; c < 8; ++c) orow[c] = a[c] + bias[nb + c];
  } else {
#pragma unroll
    for (int c = 0; c < 8; ++c)
      if (nb + c < Ncols) orow[c] = a[c] + bias[nb + c];
  }
}

extern "C" void kernel_launch(void* const* d_in, const int* in_sizes, int n_in,
                              void* d_out, int out_size, void* d_ws, size_t ws_size,
                              hipStream_t stream) {
  const float* x  = (const float*)d_in[0];
  const float* W0 = (const float*)d_in[1];
  const float* b0 = (const float*)d_in[2];
  const float* W1 = (const float*)d_in[3];
  const float* b1 = (const float*)d_in[4];
  const float* Wc = (const float*)d_in[5];
  const float* bc = (const float*)d_in[6];
  float* out = (float*)d_out;

  auto align256 = [](size_t v) { return (v + 255) & ~(size_t)255; };
  char* base = (char*)d_ws;
  size_t off = 0;
  float* W1blk = (float*)(base + off);
  off = align256(off + (size_t)H_SZ * H_SZ * sizeof(float));       // 16.8 MB
  float* Wcblk = (float*)(base + off);
  off = align256(off + (size_t)H_SZ * NC_PAD * sizeof(float));     // 8.26 MB
  const size_t fixed = off;

  const size_t per_row =
      (size_t)H_SZ * 8 + (size_t)K_TOP * 16;  // hd (f64) + pvk (longlong2)
  int chunkB = B_SZ;
  while (fixed + (size_t)chunkB * per_row + 4096 > ws_size && chunkB > 1024)
    chunkB >>= 1;

  double* hd = (double*)(base + off);
  off = align256(off + (size_t)chunkB * H_SZ * sizeof(double));
  longlong2* pvk = (longlong2*)(base + off);  // int2 view reuses same buffer

  const dim3 blk(256);
  // one-time weight pack to split-half blocked layout
  pack_w_split<<<dim3(H_SZ / 32, H_SZ / 32), dim3(32, 8), 0, stream>>>(
      W1, W1blk, H_SZ, H_SZ, H_SZ);
  pack_w_split<<<dim3(H_SZ / 32, (NC_PAD + 31) / 32), dim3(32, 8), 0,
                 stream>>>(Wc, Wcblk, NC_SZ, H_SZ, NC_PAD);

  for (int m0 = 0; m0 < B_SZ; m0 += chunkB) {
    const int M = chunkB;
    // layer 0: dense fp64 (2-way split for rocprof visibility)
    const int Mh = M / 2;
    gemm_bt_v2<<<dim3(H_SZ / 64, Mh / 128), blk, 0, stream>>>(
        x + (size_t)m0 * IN_SZ, W0, b0, hd, Mh, H_SZ, IN_SZ);
    gemm_bt_v2<<<dim3(H_SZ / 64, Mh / 128), blk, 0, stream>>>(
        x + (size_t)(m0 + Mh) * IN_SZ, W0, b0, hd + (size_t)Mh * H_SZ, Mh,
        H_SZ, IN_SZ);
    // topk #1: f64 selection, f64 emit (layer-1 pv must stay exact)
    topk_compact_v4<false><<<dim3(M), blk, 0, stream>>>(hd, (void*)pvk);
    // layer 1: f64-exact SpMM -> dense hd
    spmm8_v4d<<<dim3(H_SZ / 8, M / 1024), dim3(1024), 0, stream>>>(
        pvk, W1blk, b1, hd, H_SZ, H_SZ);
    // topk #2: f64 selection, f32 emit (layer 2 consumed (float)pv anyway)
    topk_compact_v4<true><<<dim3(M), blk, 0, stream>>>(hd, (void*)pvk);
    // layer 2: f32 SpMM -> output
    spmm8_v4f<<<dim3(NC_PAD / 8, M / 1024), dim3(1024), 0, stream>>>(
        (const int2*)pvk, Wcblk, bc, out + (size_t)m0 * NC_SZ, NC_SZ, NC_SZ);
  }
}